// Round 2
// baseline (46964.822 us; speedup 1.0000x reference)
//
#include <hip/hip_runtime.h>
#include <hip/hip_bf16.h>
#include <math.h>

typedef __hip_bfloat16 bf;

#define B_ 8
#define S_ 512
#define H_ 768
#define L_ 12
#define NH_ 12
#define HD_ 64
#define FF_ 3072
#define NC_ 6
#define BS_ (B_ * S_)          // 4096 tokens
#define BSH_ ((size_t)BS_ * H_)

// Runtime-dtype load: isbf chosen by detect_kernel from ln_emb_g's bit pattern.
__device__ __forceinline__ float LD(const void* p, size_t i, int isbf) {
    return isbf ? __bfloat162float(((const bf*)p)[i]) : ((const float*)p)[i];
}

// ---------------------------------------------------------------------------
// Detect float dtype of inputs: ln_emb_g is all ones.
// fp32: first word 0x3F800000. bf16: two 1.0 halves -> 0x3F803F80.
__global__ void detect_kernel(const unsigned int* __restrict__ g, int* __restrict__ flag) {
    if (threadIdx.x == 0 && blockIdx.x == 0)
        *flag = (g[0] == 0x3F800000u) ? 0 : 1;
}

// ---------------------------------------------------------------------------
// Relative-position sinusoid table: [129, 64]. Match numpy: fp64 math -> fp32.
__global__ void build_table_kernel(float* __restrict__ tab) {
    int idx = blockIdx.x * 256 + threadIdx.x;
    if (idx >= 129 * 64) return;
    int p = idx >> 6, d = idx & 63;
    double angle = (double)p / pow(10000.0, (double)(2 * (d / 2)) / 64.0);
    tab[idx] = (float)((d & 1) ? cos(angle) : sin(angle));
}

// ---------------------------------------------------------------------------
// Embedding sum (word + pos + type[0]) -> fp32
__global__ __launch_bounds__(256) void embed_kernel(
    const int* __restrict__ ids, const void* __restrict__ we,
    const void* __restrict__ pe, const void* __restrict__ te,
    float* __restrict__ y, const int* __restrict__ fl) {
    int isbf = *fl;
    int t = blockIdx.x;          // token 0..4095
    int s = t & (S_ - 1);
    int id = ids[t];
    size_t base = (size_t)t * H_;
    for (int c = threadIdx.x; c < H_; c += 256) {
        y[base + c] = LD(we, (size_t)id * H_ + c, isbf) +
                      LD(pe, (size_t)s * H_ + c, isbf) +
                      LD(te, c, isbf);
    }
}

// ---------------------------------------------------------------------------
// Mask bias: (1 - mask) * -10000
__global__ void maskbias_kernel(const int* __restrict__ mask, float* __restrict__ mb) {
    int t = blockIdx.x * 256 + threadIdx.x;
    if (t < BS_) mb[t] = (1.0f - (float)mask[t]) * -10000.0f;
}

// ---------------------------------------------------------------------------
// LayerNorm over H=768, one block (256 thr) per row. out = LN(a (+ resid)) * g + b
// goff = element offset into g/b. In-place safe (out may alias a or resid).
__global__ __launch_bounds__(256) void ln_kernel(
    float* out, const float* a, const float* resid,
    const void* __restrict__ g, const void* __restrict__ b, size_t goff,
    const int* __restrict__ fl) {
    __shared__ float part[256];
    int isbf = *fl;
    int tid = threadIdx.x;
    size_t base = (size_t)blockIdx.x * H_;
    float v0 = a[base + tid];
    float v1 = a[base + tid + 256];
    float v2 = a[base + tid + 512];
    if (resid) {
        v0 += resid[base + tid];
        v1 += resid[base + tid + 256];
        v2 += resid[base + tid + 512];
    }
    part[tid] = v0 + v1 + v2;
    __syncthreads();
    for (int off = 128; off > 0; off >>= 1) {
        if (tid < off) part[tid] += part[tid + off];
        __syncthreads();
    }
    float mu = part[0] * (1.0f / (float)H_);
    __syncthreads();
    float d0 = v0 - mu, d1 = v1 - mu, d2 = v2 - mu;
    part[tid] = d0 * d0 + d1 * d1 + d2 * d2;
    __syncthreads();
    for (int off = 128; off > 0; off >>= 1) {
        if (tid < off) part[tid] += part[tid + off];
        __syncthreads();
    }
    float var = part[0] * (1.0f / (float)H_);
    float rs = 1.0f / sqrtf(var + 1e-12f);
    out[base + tid]       = d0 * rs * LD(g, goff + tid, isbf)       + LD(b, goff + tid, isbf);
    out[base + tid + 256] = d1 * rs * LD(g, goff + tid + 256, isbf) + LD(b, goff + tid + 256, isbf);
    out[base + tid + 512] = d2 * rs * LD(g, goff + tid + 512, isbf) + LD(b, goff + tid + 512, isbf);
}

// ---------------------------------------------------------------------------
// GEMM: C[M,N] = A[M,K] (fp32) @ W[woff + K*N] + bias[boff + N], optional GELU.
// 64x64 tile per block, 256 threads, 4x4 per thread. M,N %64==0, K %16==0.
__global__ __launch_bounds__(256) void gemm_kernel(
    const float* __restrict__ A, const void* __restrict__ W, size_t woff,
    const void* __restrict__ bias, size_t boff, float* __restrict__ C,
    int M, int N, int K, int act, const int* __restrict__ fl) {
    __shared__ float As[16][65];
    __shared__ float Ws[16][65];
    const int isbf = *fl;
    const int tid = threadIdx.x;
    const int tx = tid & 15;   // n quad
    const int ty = tid >> 4;   // m quad
    const int m0 = blockIdx.y * 64;
    const int n0 = blockIdx.x * 64;
    float acc[4][4] = {};
    for (int k0 = 0; k0 < K; k0 += 16) {
        for (int idx = tid; idx < 1024; idx += 256) {
            int m = idx >> 4, kk = idx & 15;
            As[kk][m] = A[(size_t)(m0 + m) * K + k0 + kk];
        }
        for (int idx = tid; idx < 1024; idx += 256) {
            int kk = idx >> 6, n = idx & 63;
            Ws[kk][n] = LD(W, woff + (size_t)(k0 + kk) * N + n0 + n, isbf);
        }
        __syncthreads();
#pragma unroll
        for (int kk = 0; kk < 16; ++kk) {
            float a0 = As[kk][ty * 4 + 0];
            float a1 = As[kk][ty * 4 + 1];
            float a2 = As[kk][ty * 4 + 2];
            float a3 = As[kk][ty * 4 + 3];
            float w0 = Ws[kk][tx * 4 + 0];
            float w1 = Ws[kk][tx * 4 + 1];
            float w2 = Ws[kk][tx * 4 + 2];
            float w3 = Ws[kk][tx * 4 + 3];
            acc[0][0] += a0 * w0; acc[0][1] += a0 * w1; acc[0][2] += a0 * w2; acc[0][3] += a0 * w3;
            acc[1][0] += a1 * w0; acc[1][1] += a1 * w1; acc[1][2] += a1 * w2; acc[1][3] += a1 * w3;
            acc[2][0] += a2 * w0; acc[2][1] += a2 * w1; acc[2][2] += a2 * w2; acc[2][3] += a2 * w3;
            acc[3][0] += a3 * w0; acc[3][1] += a3 * w1; acc[3][2] += a3 * w2; acc[3][3] += a3 * w3;
        }
        __syncthreads();
    }
#pragma unroll
    for (int im = 0; im < 4; ++im) {
        size_t m = (size_t)(m0 + ty * 4 + im);
#pragma unroll
        for (int in = 0; in < 4; ++in) {
            int n = n0 + tx * 4 + in;
            float v = acc[im][in] + LD(bias, boff + n, isbf);
            if (act == 1) {  // exact gelu
                v = 0.5f * v * (1.0f + erff(v * 0.70710678118654752f));
            }
            C[m * N + n] = v;
        }
    }
}

// ---------------------------------------------------------------------------
// Attention: one block per (b, h, i) query row. Fuses rel-pos into scores and ctx.
// grid = B*NH*S, 256 threads. q,k,v are [B,S,H] fp32 with head-major layout.
__global__ __launch_bounds__(256) void attn_kernel(
    const float* __restrict__ q, const float* __restrict__ k,
    const float* __restrict__ v, const float* __restrict__ tab,
    const float* __restrict__ mb, float* __restrict__ ctx) {
    __shared__ float tabs[129 * 64];
    __shared__ float sc[S_];
    __shared__ float tq[64];
    __shared__ float part[256];
    const int tid = threadIdx.x;
    int r = blockIdx.x;
    int i = r & (S_ - 1);
    int bh = r >> 9;
    int h = bh % NH_;
    int b = bh / NH_;

    for (int idx = tid; idx < 129 * 64; idx += 256) tabs[idx] = tab[idx];
    if (tid < 64) tq[tid] = q[((size_t)(b * S_ + i)) * H_ + h * 64 + tid];
    __syncthreads();

    float lmax = -1e30f;
#pragma unroll
    for (int rep = 0; rep < 2; ++rep) {
        int j = tid + rep * 256;
        const float* kp = k + ((size_t)(b * S_ + j)) * H_ + h * 64;
        int d0 = j - i;
        d0 = d0 < -64 ? -64 : (d0 > 64 ? 64 : d0);
        const float* tp = tabs + (d0 + 64) * 64;
        float s = 0.0f;
#pragma unroll 8
        for (int d = 0; d < 64; ++d) s += tq[d] * (kp[d] + tp[d]);
        s = s * 0.125f + mb[b * S_ + j];
        sc[j] = s;
        lmax = fmaxf(lmax, s);
    }
    part[tid] = lmax;
    __syncthreads();
    for (int off = 128; off > 0; off >>= 1) {
        if (tid < off) part[tid] = fmaxf(part[tid], part[tid + off]);
        __syncthreads();
    }
    float mx = part[0];
    __syncthreads();
    float lsum = 0.0f;
#pragma unroll
    for (int rep = 0; rep < 2; ++rep) {
        int j = tid + rep * 256;
        float e = expf(sc[j] - mx);
        sc[j] = e;
        lsum += e;
    }
    part[tid] = lsum;
    __syncthreads();
    for (int off = 128; off > 0; off >>= 1) {
        if (tid < off) part[tid] += part[tid + off];
        __syncthreads();
    }
    float inv = 1.0f / part[0];
    __syncthreads();

    int d = tid & 63, g = tid >> 6;
    float acc = 0.0f;
    for (int j = g * 128; j < g * 128 + 128; ++j) {
        int d0 = j - i;
        d0 = d0 < -64 ? -64 : (d0 > 64 ? 64 : d0);
        acc += sc[j] * (v[((size_t)(b * S_ + j)) * H_ + h * 64 + d] + tabs[(d0 + 64) * 64 + d]);
    }
    part[tid] = acc;
    __syncthreads();
    if (g == 0) {
        float s = part[d] + part[64 + d] + part[128 + d] + part[192 + d];
        ctx[((size_t)(b * S_ + i)) * H_ + h * 64 + d] = s * inv;
    }
}

// ---------------------------------------------------------------------------
// Pooler: pooled[b,n] = tanh(x[b,0,:] @ pW + pb). grid = B, 256 threads.
__global__ __launch_bounds__(256) void pool_kernel(
    const float* __restrict__ x, const void* __restrict__ pW,
    const void* __restrict__ pb, float* __restrict__ pooled,
    const int* __restrict__ fl) {
    int isbf = *fl;
    int b = blockIdx.x;
    const float* xr = x + (size_t)b * S_ * H_;  // row s=0
    for (int n = threadIdx.x; n < H_; n += 256) {
        float acc = LD(pb, n, isbf);
        for (int kx = 0; kx < H_; ++kx)
            acc += xr[kx] * LD(pW, (size_t)kx * H_ + n, isbf);
        pooled[b * H_ + n] = tanhf(acc);
    }
}

// seq_avg[b,c] = mean over s of x[b,s,c]. grid = B.
__global__ __launch_bounds__(256) void seqavg_kernel(
    const float* __restrict__ x, float* __restrict__ sa) {
    int b = blockIdx.x;
    for (int c = threadIdx.x; c < H_; c += 256) {
        float s = 0.0f;
        for (int j = 0; j < S_; ++j) s += x[((size_t)b * S_ + j) * H_ + c];
        sa[b * H_ + c] = s * (1.0f / (float)S_);
    }
}

// Final head: out[b,c] = [sa, pooled] @ cls_W + cls_b. 1 block, 64 threads.
__global__ void head_kernel(const float* __restrict__ sa, const float* __restrict__ pooled,
                            const void* __restrict__ cW, const void* __restrict__ cb,
                            void* __restrict__ out, const int* __restrict__ fl) {
    int isbf = *fl;
    int t = threadIdx.x;
    if (t >= B_ * NC_) return;
    int b = t / NC_, c = t % NC_;
    float acc = LD(cb, c, isbf);
    for (int kx = 0; kx < H_; ++kx)
        acc += sa[b * H_ + kx] * LD(cW, (size_t)kx * NC_ + c, isbf);
    for (int kx = 0; kx < H_; ++kx)
        acc += pooled[b * H_ + kx] * LD(cW, (size_t)(H_ + kx) * NC_ + c, isbf);
    if (isbf) ((bf*)out)[t] = __float2bfloat16(acc);
    else      ((float*)out)[t] = acc;
}

// ---------------------------------------------------------------------------
extern "C" void kernel_launch(void* const* d_in, const int* in_sizes, int n_in,
                              void* d_out, int out_size, void* d_ws, size_t ws_size,
                              hipStream_t stream) {
    (void)in_sizes; (void)n_in; (void)out_size; (void)ws_size;
    const int* ids   = (const int*)d_in[0];
    const int* amask = (const int*)d_in[1];
    const void* we  = d_in[2];
    const void* pe  = d_in[3];
    const void* te  = d_in[4];
    const void* lng = d_in[5];
    const void* lnb = d_in[6];
    const void* Wq  = d_in[7];
    const void* bq  = d_in[8];
    const void* Wk  = d_in[9];
    const void* bk  = d_in[10];
    const void* Wv  = d_in[11];
    const void* bv  = d_in[12];
    const void* Wo  = d_in[13];
    const void* bo  = d_in[14];
    const void* l1g = d_in[15];
    const void* l1b = d_in[16];
    const void* W1  = d_in[17];
    const void* b1  = d_in[18];
    const void* W2  = d_in[19];
    const void* b2  = d_in[20];
    const void* l2g = d_in[21];
    const void* l2b = d_in[22];
    const void* pW  = d_in[23];
    const void* pb  = d_in[24];
    const void* cW  = d_in[25];
    const void* cb  = d_in[26];

    // Workspace carve-up (fp32), ~75.6 MB total.
    // FFN hidden (4096x3072) aliases r0..r3 (all dead during FFN).
    float* x    = (float*)d_ws;
    float* r0   = x  + BSH_;
    float* r1   = r0 + BSH_;
    float* r2   = r1 + BSH_;
    float* r3   = r2 + BSH_;
    float* z    = r3 + BSH_;
    float* tab  = z  + BSH_;               // [129,64]
    float* mb   = tab + 129 * 64;          // [4096]
    float* pool = mb + BS_;                // [8,768]
    float* sa   = pool + B_ * H_;          // [8,768]
    int*   flag = (int*)(sa + B_ * H_);
    float* hb   = r0;                      // [4096,3072] alias of r0..r3

    detect_kernel<<<1, 64, 0, stream>>>((const unsigned int*)lng, flag);
    build_table_kernel<<<(129 * 64 + 255) / 256, 256, 0, stream>>>(tab);
    maskbias_kernel<<<(BS_ + 255) / 256, 256, 0, stream>>>(amask, mb);
    embed_kernel<<<BS_, 256, 0, stream>>>(ids, we, pe, te, r0, flag);
    ln_kernel<<<BS_, 256, 0, stream>>>(x, r0, nullptr, lng, lnb, 0, flag);

    dim3 gH(H_ / 64, BS_ / 64);    // N=768
    dim3 gF(FF_ / 64, BS_ / 64);   // N=3072

    for (int l = 0; l < L_; ++l) {
        const size_t oHH = (size_t)l * H_ * H_;
        const size_t oH  = (size_t)l * H_;
        const size_t oHF = (size_t)l * H_ * FF_;
        const size_t oF  = (size_t)l * FF_;
        gemm_kernel<<<gH, 256, 0, stream>>>(x, Wq, oHH, bq, oH, r1, BS_, H_, H_, 0, flag);
        gemm_kernel<<<gH, 256, 0, stream>>>(x, Wk, oHH, bk, oH, r2, BS_, H_, H_, 0, flag);
        gemm_kernel<<<gH, 256, 0, stream>>>(x, Wv, oHH, bv, oH, r3, BS_, H_, H_, 0, flag);
        attn_kernel<<<B_ * NH_ * S_, 256, 0, stream>>>(r1, r2, r3, tab, mb, r0);
        gemm_kernel<<<gH, 256, 0, stream>>>(r0, Wo, oHH, bo, oH, r1, BS_, H_, H_, 0, flag);
        ln_kernel<<<BS_, 256, 0, stream>>>(x, r1, x, l1g, l1b, oH, flag);
        gemm_kernel<<<gF, 256, 0, stream>>>(x, W1, oHF, b1, oF, hb, BS_, FF_, H_, 1, flag);
        gemm_kernel<<<gH, 256, 0, stream>>>(hb, W2, oHF, b2, oH, z, BS_, H_, FF_, 0, flag);
        ln_kernel<<<BS_, 256, 0, stream>>>(x, z, x, l2g, l2b, oH, flag);
    }

    pool_kernel<<<B_, 256, 0, stream>>>(x, pW, pb, pool, flag);
    seqavg_kernel<<<B_, 256, 0, stream>>>(x, sa);
    head_kernel<<<1, 64, 0, stream>>>(sa, pool, cW, cb, d_out, flag);
}